// Round 2
// baseline (282.251 us; speedup 1.0000x reference)
//
#include <hip/hip_runtime.h>

namespace {

constexpr int kCont  = 64;
constexpr int kNCate = 16;
constexpr int kEm    = 8;
constexpr int kRH    = 32;
constexpr int kR     = 32;
constexpr int kPH    = 16;
constexpr int kVocab = 1000;
constexpr size_t kTableElems = (size_t)kNCate * kVocab * kRH;   // 512000 floats = 2 MB

// ---------------------------------------------------------------------------
// Precompute T[c][v][j] = sum_k emb[c][v][k] * W1[64 + c*8 + k][j]
// One thread per (c, v, j4) where j4 indexes a float4 of the 32 outputs.
// 16*1000*8 = 128000 threads, 32 FMA each. Runs every call (deterministic).
// ---------------------------------------------------------------------------
__global__ __launch_bounds__(256) void build_emb_table(
    const float* __restrict__ emb,
    const float* __restrict__ W1,
    float* __restrict__ T)
{
    const int gid = blockIdx.x * blockDim.x + threadIdx.x;
    constexpr int total = kNCate * kVocab * (kRH / 4);
    if (gid >= total) return;

    const int j4 = gid & 7;          // which float4 of the 32 outputs
    const int cv = gid >> 3;         // c*1000 + v
    const int c  = cv / kVocab;

    const float* ep = emb + (size_t)cv * kEm;
    const float* w  = W1 + (size_t)(kCont + c * kEm) * kRH + j4 * 4;

    float4 acc = {0.f, 0.f, 0.f, 0.f};
#pragma unroll
    for (int k = 0; k < kEm; ++k) {
        const float e = ep[k];
        const float* wr = w + (size_t)k * kRH;
        acc.x = fmaf(e, wr[0], acc.x);
        acc.y = fmaf(e, wr[1], acc.y);
        acc.z = fmaf(e, wr[2], acc.z);
        acc.w = fmaf(e, wr[3], acc.w);
    }
    reinterpret_cast<float4*>(T)[(size_t)cv * 8 + j4] = acc;
}

// ---------------------------------------------------------------------------
// Main fused kernel. USE_TABLE: layer-1 embedding contribution comes from the
// precomputed T (16 gathers of 128 B + adds) instead of emb gathers + FMAs.
// ---------------------------------------------------------------------------
template <bool USE_TABLE>
__global__ __launch_bounds__(256) void fused_mlp(
    const float* __restrict__ x_cont,
    const int*   __restrict__ x_cate,
    const int*   __restrict__ t,
    const float* __restrict__ emb,
    const float* __restrict__ T,
    const float* __restrict__ W1,
    const float* __restrict__ b1,
    const float* __restrict__ W2,
    const float* __restrict__ b2,
    const float* __restrict__ W3,
    const float* __restrict__ b3,
    const float* __restrict__ HW1,
    const float* __restrict__ Hb1,
    const float* __restrict__ HW2,
    const float* __restrict__ Hb2,
    float* __restrict__ out,
    int nrows)
{
    const int row = blockIdx.x * blockDim.x + threadIdx.x;
    if (row >= nrows) return;

    // ---------------- layer 1: h1 = relu(x @ W1 + b1) ----------------
    float h1[kRH];
#pragma unroll
    for (int j = 0; j < kRH; ++j) h1[j] = b1[j];

    // embedding contribution
    if (USE_TABLE) {
        int idx[kNCate];
        const int4* cr4 = reinterpret_cast<const int4*>(x_cate + (size_t)row * kNCate);
#pragma unroll
        for (int g = 0; g < kNCate / 4; ++g) {
            int4 a = cr4[g];
            idx[g * 4 + 0] = a.x; idx[g * 4 + 1] = a.y;
            idx[g * 4 + 2] = a.z; idx[g * 4 + 3] = a.w;
        }
#pragma unroll
        for (int c = 0; c < kNCate; ++c) {
            const float4* tp = reinterpret_cast<const float4*>(
                T + ((size_t)c * kVocab + (size_t)idx[c]) * kRH);
#pragma unroll
            for (int j4 = 0; j4 < kRH / 4; ++j4) {
                float4 v = tp[j4];
                h1[j4 * 4 + 0] += v.x;
                h1[j4 * 4 + 1] += v.y;
                h1[j4 * 4 + 2] += v.z;
                h1[j4 * 4 + 3] += v.w;
            }
        }
    } else {
        const int* cr = x_cate + (size_t)row * kNCate;
#pragma unroll 2
        for (int c = 0; c < kNCate; ++c) {
            const int idx = cr[c];
            const float* ep = emb + ((size_t)c * kVocab + (size_t)idx) * kEm;
            float4 a = *reinterpret_cast<const float4*>(ep);
            float4 b = *reinterpret_cast<const float4*>(ep + 4);
            float xs[8] = {a.x, a.y, a.z, a.w, b.x, b.y, b.z, b.w};
            const float* w = W1 + (size_t)(kCont + c * kEm) * kRH;
#pragma unroll
            for (int kk = 0; kk < 8; ++kk)
#pragma unroll
                for (int j = 0; j < kRH; ++j)
                    h1[j] = fmaf(xs[kk], w[kk * kRH + j], h1[j]);
        }
    }

    // continuous contribution: 64 features, chunks of 8, wave-uniform weights
    const float* xr = x_cont + (size_t)row * kCont;
#pragma unroll 2
    for (int k0 = 0; k0 < kCont; k0 += 8) {
        float4 a = *reinterpret_cast<const float4*>(xr + k0);
        float4 b = *reinterpret_cast<const float4*>(xr + k0 + 4);
        float xs[8] = {a.x, a.y, a.z, a.w, b.x, b.y, b.z, b.w};
        const float* w = W1 + (size_t)k0 * kRH;
#pragma unroll
        for (int kk = 0; kk < 8; ++kk)
#pragma unroll
            for (int j = 0; j < kRH; ++j)
                h1[j] = fmaf(xs[kk], w[kk * kRH + j], h1[j]);
    }

#pragma unroll
    for (int j = 0; j < kRH; ++j) h1[j] = fmaxf(h1[j], 0.0f);

    // ---------------- layer 2: h2 = relu(h1 @ W2 + b2) ----------------
    float h2[kRH];
#pragma unroll
    for (int j = 0; j < kRH; ++j) h2[j] = b2[j];
#pragma unroll 4
    for (int k = 0; k < kRH; ++k) {
        const float hk = h1[k];
        const float* w = W2 + (size_t)k * kRH;
#pragma unroll
        for (int j = 0; j < kRH; ++j)
            h2[j] = fmaf(hk, w[j], h2[j]);
    }
#pragma unroll
    for (int j = 0; j < kRH; ++j) h2[j] = fmaxf(h2[j], 0.0f);

    // ---------------- layer 3: r = h2 @ W3 + b3 ----------------
    float r[kR];
#pragma unroll
    for (int j = 0; j < kR; ++j) r[j] = b3[j];
#pragma unroll 4
    for (int k = 0; k < kRH; ++k) {
        const float hk = h2[k];
        const float* w = W3 + (size_t)k * kR;
#pragma unroll
        for (int j = 0; j < kR; ++j)
            r[j] = fmaf(hk, w[j], r[j]);
    }

    // ---------------- selected head ----------------
    const int head = t[row];
    const float* hw1 = HW1 + (size_t)head * kR * kPH;
    const float* hb1 = Hb1 + (size_t)head * kPH;

    float hh[kPH];
#pragma unroll
    for (int j = 0; j < kPH; ++j) hh[j] = hb1[j];
#pragma unroll 4
    for (int k = 0; k < kR; ++k) {
        const float rk = r[k];
        const float* w = hw1 + (size_t)k * kPH;
#pragma unroll
        for (int j = 0; j < kPH; ++j)
            hh[j] = fmaf(rk, w[j], hh[j]);
    }

    const float* hw2 = HW2 + (size_t)head * kPH;
    float y = Hb2[head];
#pragma unroll
    for (int j = 0; j < kPH; ++j)
        y = fmaf(fmaxf(hh[j], 0.0f), hw2[j], y);

    out[row] = y;
}

} // namespace

extern "C" void kernel_launch(void* const* d_in, const int* in_sizes, int n_in,
                              void* d_out, int out_size, void* d_ws, size_t ws_size,
                              hipStream_t stream)
{
    const float* x_cont = (const float*)d_in[0];
    const int*   x_cate = (const int*)  d_in[1];
    const int*   t      = (const int*)  d_in[2];
    const float* emb    = (const float*)d_in[3];
    const float* W1     = (const float*)d_in[4];
    const float* b1     = (const float*)d_in[5];
    const float* W2     = (const float*)d_in[6];
    const float* b2     = (const float*)d_in[7];
    const float* W3     = (const float*)d_in[8];
    const float* b3     = (const float*)d_in[9];
    const float* HW1    = (const float*)d_in[10];
    const float* Hb1    = (const float*)d_in[11];
    const float* HW2    = (const float*)d_in[12];
    const float* Hb2    = (const float*)d_in[13];
    float* out = (float*)d_out;

    const int nrows = out_size;            // 524288
    const bool use_table = ws_size >= kTableElems * sizeof(float);
    float* T = (float*)d_ws;

    if (use_table) {
        constexpr int tbuild = kNCate * kVocab * (kRH / 4);      // 128000 threads
        hipLaunchKernelGGL(build_emb_table, dim3((tbuild + 255) / 256), dim3(256),
                           0, stream, emb, W1, T);
    }

    const int block = 256;
    const int grid  = (nrows + block - 1) / block;   // 2048 blocks
    if (use_table) {
        hipLaunchKernelGGL((fused_mlp<true>), dim3(grid), dim3(block), 0, stream,
                           x_cont, x_cate, t, emb, T, W1, b1, W2, b2, W3, b3,
                           HW1, Hb1, HW2, Hb2, out, nrows);
    } else {
        hipLaunchKernelGGL((fused_mlp<false>), dim3(grid), dim3(block), 0, stream,
                           x_cont, x_cate, t, emb, T, W1, b1, W2, b2, W3, b3,
                           HW1, Hb1, HW2, Hb2, out, nrows);
    }
}

// Round 3
// 196.808 us; speedup vs baseline: 1.4341x; 1.4341x over previous
//
#include <hip/hip_runtime.h>

namespace {

typedef float f4 __attribute__((ext_vector_type(4)));
typedef int   i4 __attribute__((ext_vector_type(4)));

constexpr int kCont  = 64;
constexpr int kNCate = 16;
constexpr int kRH    = 32;
constexpr int kR     = 32;
constexpr int kPH    = 16;
constexpr int kVocab = 1000;
constexpr int kNHead = 8;
constexpr int kHPad  = 524;   // LDS floats per head slab: 512 + 12 pad
                              // head h starts at bank (524*h)%32 = 12h%32 -> all 8 distinct

__global__ __launch_bounds__(256, 3) void fused_mlp(
    const float* __restrict__ x_cont,
    const int*   __restrict__ x_cate,
    const int*   __restrict__ t,
    const float* __restrict__ emb,
    const float* __restrict__ W1,
    const float* __restrict__ b1,
    const float* __restrict__ W2,
    const float* __restrict__ b2,
    const float* __restrict__ W3,
    const float* __restrict__ b3,
    const float* __restrict__ HW1,
    const float* __restrict__ Hb1,
    const float* __restrict__ HW2,
    const float* __restrict__ Hb2,
    float* __restrict__ out,
    int nrows)
{
    __shared__ float sHW1[kNHead * kHPad];   // ~16.8 KB
    __shared__ float sHW2[kNHead * kPH];
    __shared__ float sHb1[kNHead * kPH];
    __shared__ float sHb2[kNHead];

    const int tid = threadIdx.x;

    // ---- stage head weights into LDS (coalesced reads, padded per head) ----
    {
        const f4* g1 = reinterpret_cast<const f4*>(HW1);   // 8*512 floats = 1024 f4
#pragma unroll
        for (int i = 0; i < 4; ++i) {
            const int g4 = tid + i * 256;     // 0..1023
            const int n  = g4 >> 7;           // head = g4/128
            const int r4 = g4 & 127;
            *reinterpret_cast<f4*>(&sHW1[n * kHPad + r4 * 4]) = g1[g4];
        }
        if (tid < 32) {
            reinterpret_cast<f4*>(sHW2)[tid] = reinterpret_cast<const f4*>(HW2)[tid];
        } else if (tid < 64) {
            reinterpret_cast<f4*>(sHb1)[tid - 32] = reinterpret_cast<const f4*>(Hb1)[tid - 32];
        } else if (tid < 72) {
            sHb2[tid - 64] = Hb2[tid - 64];
        }
    }
    __syncthreads();

    const int row = blockIdx.x * blockDim.x + tid;
    if (row >= nrows) return;

    const int head = __builtin_nontemporal_load(&t[row]);

    // ---- categorical indices: 4 x int4 ----
    int idx[kNCate];
    {
        const i4* cr4 = reinterpret_cast<const i4*>(x_cate + (size_t)row * kNCate);
#pragma unroll
        for (int g = 0; g < 4; ++g) {
            i4 a = __builtin_nontemporal_load(&cr4[g]);
            idx[4 * g + 0] = a[0];
            idx[4 * g + 1] = a[1];
            idx[4 * g + 2] = a[2];
            idx[4 * g + 3] = a[3];
        }
    }

    float h1[kRH];
#pragma unroll
    for (int j = 0; j < kRH; ++j) h1[j] = b1[j];

    const f4* eb = reinterpret_cast<const f4*>(emb);

    // ---- issue x_cont loads (16 f4) and emb pass1 (cates 0..7, 16 f4) ----
    f4 xc[16];
    {
        const f4* xr = reinterpret_cast<const f4*>(x_cont + (size_t)row * kCont);
#pragma unroll
        for (int i = 0; i < 16; ++i) xc[i] = __builtin_nontemporal_load(&xr[i]);
    }

    f4 e1[16];
#pragma unroll
    for (int c = 0; c < 8; ++c) {
        const int o4 = (c * kVocab + idx[c]) * 2;   // f4 units, 32 B rows
        e1[2 * c]     = eb[o4];
        e1[2 * c + 1] = eb[o4 + 1];
    }

    // ---- consume x_cont: k = 4i+kk, wave-uniform W1 rows via s_load ----
#pragma unroll
    for (int i = 0; i < 16; ++i) {
#pragma unroll
        for (int kk = 0; kk < 4; ++kk) {
            const float xv = xc[i][kk];
            const float* w = W1 + (size_t)(i * 4 + kk) * kRH;
#pragma unroll
            for (int j = 0; j < kRH; ++j)
                h1[j] = fmaf(xv, w[j], h1[j]);
        }
    }

    // ---- issue emb pass2 (cates 8..15) so it flies under pass1's FMAs ----
    f4 e2[16];
#pragma unroll
    for (int c = 0; c < 8; ++c) {
        const int o4 = ((c + 8) * kVocab + idx[c + 8]) * 2;
        e2[2 * c]     = eb[o4];
        e2[2 * c + 1] = eb[o4 + 1];
    }

    // ---- consume emb pass1: cate c -> W1 rows 64+8c .. 64+8c+7 ----
#pragma unroll
    for (int c = 0; c < 8; ++c) {
#pragma unroll
        for (int half = 0; half < 2; ++half) {
#pragma unroll
            for (int kk = 0; kk < 4; ++kk) {
                const float ev = e1[2 * c + half][kk];
                const float* w = W1 + (size_t)(kCont + c * 8 + half * 4 + kk) * kRH;
#pragma unroll
                for (int j = 0; j < kRH; ++j)
                    h1[j] = fmaf(ev, w[j], h1[j]);
            }
        }
    }

    // ---- consume emb pass2 ----
#pragma unroll
    for (int c = 0; c < 8; ++c) {
#pragma unroll
        for (int half = 0; half < 2; ++half) {
#pragma unroll
            for (int kk = 0; kk < 4; ++kk) {
                const float ev = e2[2 * c + half][kk];
                const float* w = W1 + (size_t)(kCont + (c + 8) * 8 + half * 4 + kk) * kRH;
#pragma unroll
                for (int j = 0; j < kRH; ++j)
                    h1[j] = fmaf(ev, w[j], h1[j]);
            }
        }
    }

#pragma unroll
    for (int j = 0; j < kRH; ++j) h1[j] = fmaxf(h1[j], 0.0f);

    // ---- layer 2 ----
    float h2[kRH];
#pragma unroll
    for (int j = 0; j < kRH; ++j) h2[j] = b2[j];
#pragma unroll
    for (int k = 0; k < kRH; ++k) {
        const float hk = h1[k];
        const float* w = W2 + (size_t)k * kRH;
#pragma unroll
        for (int j = 0; j < kRH; ++j)
            h2[j] = fmaf(hk, w[j], h2[j]);
    }
#pragma unroll
    for (int j = 0; j < kRH; ++j) h2[j] = fmaxf(h2[j], 0.0f);

    // ---- layer 3 ----
    float r[kR];
#pragma unroll
    for (int j = 0; j < kR; ++j) r[j] = b3[j];
#pragma unroll
    for (int k = 0; k < kRH; ++k) {
        const float hk = h2[k];
        const float* w = W3 + (size_t)k * kR;
#pragma unroll
        for (int j = 0; j < kR; ++j)
            r[j] = fmaf(hk, w[j], r[j]);
    }

    // ---- selected head, weights from LDS (bank-conflict-free pad) ----
    float hh[kPH];
    {
        const float* hb = &sHb1[head * kPH];
#pragma unroll
        for (int j4 = 0; j4 < 4; ++j4) {
            f4 v = *reinterpret_cast<const f4*>(hb + 4 * j4);
            hh[4 * j4 + 0] = v[0];
            hh[4 * j4 + 1] = v[1];
            hh[4 * j4 + 2] = v[2];
            hh[4 * j4 + 3] = v[3];
        }
    }
    const float* hwbase = &sHW1[head * kHPad];
#pragma unroll
    for (int k = 0; k < kR; ++k) {
        const float rk = r[k];
        const float* wr = hwbase + k * kPH;
#pragma unroll
        for (int j4 = 0; j4 < 4; ++j4) {
            f4 w = *reinterpret_cast<const f4*>(wr + 4 * j4);
            hh[4 * j4 + 0] = fmaf(rk, w[0], hh[4 * j4 + 0]);
            hh[4 * j4 + 1] = fmaf(rk, w[1], hh[4 * j4 + 1]);
            hh[4 * j4 + 2] = fmaf(rk, w[2], hh[4 * j4 + 2]);
            hh[4 * j4 + 3] = fmaf(rk, w[3], hh[4 * j4 + 3]);
        }
    }

    float y = sHb2[head];
    {
        const float* w2p = &sHW2[head * kPH];
#pragma unroll
        for (int j4 = 0; j4 < 4; ++j4) {
            f4 w = *reinterpret_cast<const f4*>(w2p + 4 * j4);
#pragma unroll
            for (int jj = 0; jj < 4; ++jj)
                y = fmaf(fmaxf(hh[4 * j4 + jj], 0.0f), w[jj], y);
        }
    }

    __builtin_nontemporal_store(y, &out[row]);
}

} // namespace

extern "C" void kernel_launch(void* const* d_in, const int* in_sizes, int n_in,
                              void* d_out, int out_size, void* d_ws, size_t ws_size,
                              hipStream_t stream)
{
    const float* x_cont = (const float*)d_in[0];
    const int*   x_cate = (const int*)  d_in[1];
    const int*   t      = (const int*)  d_in[2];
    const float* emb    = (const float*)d_in[3];
    const float* W1     = (const float*)d_in[4];
    const float* b1     = (const float*)d_in[5];
    const float* W2     = (const float*)d_in[6];
    const float* b2     = (const float*)d_in[7];
    const float* W3     = (const float*)d_in[8];
    const float* b3     = (const float*)d_in[9];
    const float* HW1    = (const float*)d_in[10];
    const float* Hb1    = (const float*)d_in[11];
    const float* HW2    = (const float*)d_in[12];
    const float* Hb2    = (const float*)d_in[13];
    float* out = (float*)d_out;

    const int nrows = out_size;            // 524288
    const int block = 256;
    const int grid  = (nrows + block - 1) / block;   // 2048
    hipLaunchKernelGGL(fused_mlp, dim3(grid), dim3(block), 0, stream,
                       x_cont, x_cate, t, emb, W1, b1, W2, b2, W3, b3,
                       HW1, Hb1, HW2, Hb2, out, nrows);
}

// Round 6
// 156.804 us; speedup vs baseline: 1.8000x; 1.2551x over previous
//
#include <hip/hip_runtime.h>

namespace {

typedef float  f32x4  __attribute__((ext_vector_type(4)));
typedef float  f32x16 __attribute__((ext_vector_type(16)));
typedef short  bf16x8 __attribute__((ext_vector_type(8)));
typedef unsigned int u32;

constexpr int kRows  = 524288;
constexpr int kCont  = 64;
constexpr int kNCate = 16;
constexpr int kVocab = 1000;
constexpr int kEm    = 8;
constexpr int kRH    = 32;
constexpr int kPH    = 16;

// workspace layout (bytes)
constexpr int    kNFrag = 48;                       // 12 W1h + 12 W1l + 4 W2 + 4 W3 + 16 HW1
constexpr size_t kOffEH = (size_t)kNFrag * 1024;    // 49152
constexpr size_t kOffEL = kOffEH + 256000;

__device__ inline u32 rne_hi(float x) {
    u32 u = __float_as_uint(x);
    return ((u + 0x7fffu + ((u >> 16) & 1u)) >> 16) & 0xffffu;
}
__device__ inline float hi_f32(u32 h) { return __uint_as_float(h << 16); }
__device__ inline u32 pack_split(float x) {
    u32 h = rne_hi(x);
    u32 lo = rne_hi(x - hi_f32(h));
    return h | (lo << 16);
}

union FragU { u32 w[4]; bf16x8 v; uint4 u4; };

__device__ inline f32x16 mfma16(bf16x8 a, bf16x8 b, f32x16 c) {
    return __builtin_amdgcn_mfma_f32_32x32x16_bf16(a, b, c, 0, 0, 0);
}
__device__ inline f32x16 zero16() {
    f32x16 z;
#pragma unroll
    for (int i = 0; i < 16; ++i) z[i] = 0.f;
    return z;
}
__device__ inline void lds_fence() {
    asm volatile("s_waitcnt lgkmcnt(0)" ::: "memory");
    __builtin_amdgcn_sched_barrier(0);
}
template <int CTRL>
__device__ inline float dpp_add(float v) {
    int m = __builtin_amdgcn_update_dpp(0, __float_as_int(v), CTRL, 0xF, 0xF, true);
    return v + __int_as_float(m);
}

// ---------------------------------------------------------------------------
// Pre-kernel 1: weights -> bf16 hi/lo fragments, frag-ordered for coalesced
// per-lane loads. Frag q holds 64 lanes x 8 bf16 (16B/lane).
// lane l: lc = l&31, g = l>>5;  element j: k = k0 + j.
//  q  0..11 : W1 hi, f=q     : k0=16f+8g, col=lc        (W1 is [192][32])
//  q 12..23 : W1 lo, f=q-12
//  q 24..27 : W2 (f=(q-24)>>1, p=(q-24)&1), k0=16f+8g, col=lc
//  q 28..31 : W3 same
//  q 32..47 : HW1 (u=q-32: n=u>>2, f=(u>>1)&1, p=u&1), col128 = n*32+lc,
//             head=col128>>4, ph=col128&15; element = HW1[head][k][ph]
// ---------------------------------------------------------------------------
__global__ __launch_bounds__(256) void build_wfrags(
    const float* __restrict__ W1, const float* __restrict__ W2,
    const float* __restrict__ W3, const float* __restrict__ HW1,
    ushort* __restrict__ WF)
{
    int gid = blockIdx.x * blockDim.x + threadIdx.x;
    if (gid >= kNFrag * 64) return;
    const int q = gid >> 6, l = gid & 63;
    const int lc = l & 31, g = l >> 5;

    const float* src; int k0, col, ldn, p;
    if (q < 12)      { src = W1; k0 = 16*q + 8*g;      col = lc; ldn = 32; p = 0; }
    else if (q < 24) { src = W1; k0 = 16*(q-12) + 8*g; col = lc; ldn = 32; p = 1; }
    else if (q < 28) { int u2 = q-24; src = W2; k0 = 16*(u2>>1) + 8*g; col = lc; ldn = 32; p = u2&1; }
    else if (q < 32) { int u2 = q-28; src = W3; k0 = 16*(u2>>1) + 8*g; col = lc; ldn = 32; p = u2&1; }
    else {
        int u2 = q-32; int n = u2>>2; int f = (u2>>1)&1; p = u2&1;
        int c128 = n*32 + lc; int head = c128 >> 4, ph = c128 & 15;
        src = HW1 + (size_t)head * kRH * kPH + ph;
        k0 = 16*f + 8*g; col = 0; ldn = kPH;
    }

    u32 hv[8];
#pragma unroll
    for (int j = 0; j < 8; ++j) {
        float w = src[(size_t)(k0 + j) * ldn + col];
        u32 h = rne_hi(w);
        hv[j] = (p == 0) ? h : rne_hi(w - hi_f32(h));
    }
    FragU fu;
#pragma unroll
    for (int w = 0; w < 4; ++w) fu.w[w] = hv[2*w] | (hv[2*w+1] << 16);
    ((uint4*)WF)[q * 64 + l] = fu.u4;
}

// ---------------------------------------------------------------------------
// Pre-kernel 2: emb (16*1000 rows x 8 f32) -> bf16 hi/lo tables, 16B rows.
// ---------------------------------------------------------------------------
__global__ __launch_bounds__(256) void build_embsplit(
    const float* __restrict__ emb, ushort* __restrict__ eh, ushort* __restrict__ el)
{
    int r = blockIdx.x * blockDim.x + threadIdx.x;    // row = c*1000+v
    if (r >= kNCate * kVocab) return;
    const float* e = emb + (size_t)r * kEm;
    FragU H, L;
#pragma unroll
    for (int w = 0; w < 4; ++w) {
        float a = e[2*w], b = e[2*w+1];
        u32 ha = rne_hi(a), hb_ = rne_hi(b);
        u32 la = rne_hi(a - hi_f32(ha)), lb = rne_hi(b - hi_f32(hb_));
        H.w[w] = ha | (hb_ << 16);
        L.w[w] = la | (lb << 16);
    }
    ((uint4*)eh)[r] = H.u4;
    ((uint4*)el)[r] = L.u4;
}

// ---------------------------------------------------------------------------
// Main kernel. 256 threads = 4 waves; each wave owns 64 rows = 2 M-tiles of 32.
// Split-precision MFMA (Ah*Bh + Ah*Bl + Al*Bh) on 32x32x16 bf16.
// C-layout (verified): col = lane&31, row = (reg&3) + 8*(reg>>2) + 4*(lane>>5).
// A/B frag: row/col = lane&31, k = (lane>>5)*8 + j  (self-consistent both sides).
// LDS: slots 0..19 = frags q=12..31; slots 20..27 = HW1-hi (q=32+4n+2f2).
// HW1-lo frags read directly from global (L1/L2-resident, once per M-tile).
// ---------------------------------------------------------------------------
__global__ __launch_bounds__(256, 3) void fused_main(
    const float* __restrict__ xc, const int* __restrict__ xcate,
    const int* __restrict__ tptr,
    const ushort* __restrict__ WF,
    const ushort* __restrict__ embh, const ushort* __restrict__ embl,
    const float* __restrict__ b1, const float* __restrict__ b2,
    const float* __restrict__ b3, const float* __restrict__ Hb1,
    const float* __restrict__ HW2, const float* __restrict__ Hb2,
    float* __restrict__ out)
{
    __shared__ __align__(16) ushort sW[28 * 512];   // 28 KB
    __shared__ u32 sH[4][32 * 33];                  // per-wave transition buf, 16.5 KB

    const int tid = threadIdx.x;
    const uint4* wf4 = (const uint4*)WF;

    // stage LDS frags: q=12..31 contiguous (1280 uint4), then 8 HW1-hi frags
    {
        uint4* dst = (uint4*)sW;
#pragma unroll
        for (int i = 0; i < 5; ++i)
            dst[tid + 256*i] = wf4[12*64 + tid + 256*i];
#pragma unroll
        for (int i = 0; i < 2; ++i) {
            const int idx = tid + 256*i;             // 0..511
            const int e = idx >> 6, l2 = idx & 63;   // e = 2n+f2
            const int q = 32 + 4*(e >> 1) + 2*(e & 1);
            dst[1280 + idx] = wf4[q*64 + l2];
        }
    }
    __syncthreads();

    const int wv = tid >> 6, l = tid & 63;
    const int lc = l & 31, g = l >> 5;
    const uint4* sw4 = (const uint4*)sW;

    // W1 hi fragments resident in VGPRs (12 x 16B)
    bf16x8 w1h[12];
    {
#pragma unroll
        for (int f = 0; f < 12; ++f) { FragU fu; fu.u4 = wf4[f*64 + l]; w1h[f] = fu.v; }
    }

    const float bias1 = b1[lc], bias2 = b2[lc], bias3 = b3[lc];
    const int hh_half = lc >> 4, hp = lc & 15;
    float hb1v[4], hw2v[4];
#pragma unroll
    for (int n = 0; n < 4; ++n) {
        const int head = n*2 + hh_half;
        hb1v[n] = Hb1[head * kPH + hp];
        hw2v[n] = HW2[head * kPH + hp];
    }

    u32* hb = &sH[wv][0];
    const int rowbase = blockIdx.x * 256 + wv * 64;

#pragma unroll 1
    for (int mt = 0; mt < 2; ++mt) {
        const int tb = rowbase + mt * 32;
        const int arow = tb + lc;          // this lane's A-row

        // ---- issue loads ----
        const int* crow = xcate + (size_t)arow * kNCate;
        int idxv[8];
#pragma unroll
        for (int i = 0; i < 8; ++i) idxv[i] = crow[2*i + g];

        const f32x4* xr4 = (const f32x4*)(xc + (size_t)arow * kCont);
        f32x4 xa[8];
#pragma unroll
        for (int f = 0; f < 4; ++f) { xa[2*f] = xr4[4*f + 2*g]; xa[2*f+1] = xr4[4*f + 2*g + 1]; }

        uint4 ehv[8], elv[8];
#pragma unroll
        for (int i = 0; i < 8; ++i) {
            const int c = 2*i + g;
            const size_t ro = (size_t)(c * kVocab + idxv[i]);
            ehv[i] = ((const uint4*)embh)[ro];
            elv[i] = ((const uint4*)embl)[ro];
        }

        int t_r[16];
#pragma unroll
        for (int reg = 0; reg < 16; ++reg) {
            const int row = (reg & 3) + 8*(reg >> 2) + 4*g;
            t_r[reg] = tptr[tb + row];
        }

        // ---- layer 1: 12 k-frags x 3 products, two independent acc chains ----
        f32x16 acca = zero16(), accb = zero16();
#pragma unroll
        for (int f = 0; f < 4; ++f) {       // x_cont frags (runtime split)
            float v[8] = {xa[2*f][0], xa[2*f][1], xa[2*f][2], xa[2*f][3],
                          xa[2*f+1][0], xa[2*f+1][1], xa[2*f+1][2], xa[2*f+1][3]};
            FragU H, L;
#pragma unroll
            for (int w = 0; w < 4; ++w) {
                u32 h0 = rne_hi(v[2*w]),  h1 = rne_hi(v[2*w+1]);
                u32 l0 = rne_hi(v[2*w]   - hi_f32(h0));
                u32 l1 = rne_hi(v[2*w+1] - hi_f32(h1));
                H.w[w] = h0 | (h1 << 16);
                L.w[w] = l0 | (l1 << 16);
            }
            FragU WL; WL.u4 = sw4[f*64 + l];          // W1 lo frag f
            f32x16& acc = (f & 1) ? accb : acca;
            acc = mfma16(H.v, w1h[f], acc);
            acc = mfma16(H.v, WL.v,  acc);
            acc = mfma16(L.v, w1h[f], acc);
        }
#pragma unroll
        for (int i = 0; i < 8; ++i) {       // emb frags (pre-split)
            const int f = 4 + i;
            FragU AH, AL, WL;
            AH.u4 = ehv[i]; AL.u4 = elv[i];
            WL.u4 = sw4[f*64 + l];
            f32x16& acc = (f & 1) ? accb : acca;
            acc = mfma16(AH.v, w1h[f], acc);
            acc = mfma16(AH.v, WL.v,  acc);
            acc = mfma16(AL.v, w1h[f], acc);
        }

        // ---- L1 -> L2 transition (bias, relu, split, pack to LDS) ----
#pragma unroll
        for (int reg = 0; reg < 16; ++reg) {
            const int row = (reg & 3) + 8*(reg >> 2) + 4*g;
            const float v = fmaxf(acca[reg] + accb[reg] + bias1, 0.f);
            hb[row * 33 + lc] = pack_split(v);
        }
        lds_fence();
        bf16x8 a2h[2], a2l[2];
#pragma unroll
        for (int f2 = 0; f2 < 2; ++f2) {
            u32 hv[8];
#pragma unroll
            for (int j = 0; j < 8; ++j) hv[j] = hb[lc*33 + f2*16 + 8*g + j];
            FragU H, L;
#pragma unroll
            for (int w = 0; w < 4; ++w) {
                H.w[w] = (hv[2*w] & 0xffffu) | (hv[2*w+1] << 16);
                L.w[w] = (hv[2*w] >> 16)    | (hv[2*w+1] & 0xffff0000u);
            }
            a2h[f2] = H.v; a2l[f2] = L.v;
        }

        // ---- layer 2 ----
        f32x16 acc2 = zero16();
#pragma unroll
        for (int f2 = 0; f2 < 2; ++f2) {
            FragU WH, WL;
            WH.u4 = sw4[(12 + 2*f2) * 64 + l];
            WL.u4 = sw4[(13 + 2*f2) * 64 + l];
            acc2 = mfma16(a2h[f2], WH.v, acc2);
            acc2 = mfma16(a2h[f2], WL.v, acc2);
            acc2 = mfma16(a2l[f2], WH.v, acc2);
        }
#pragma unroll
        for (int reg = 0; reg < 16; ++reg) {
            const int row = (reg & 3) + 8*(reg >> 2) + 4*g;
            const float v = fmaxf(acc2[reg] + bias2, 0.f);
            hb[row * 33 + lc] = pack_split(v);
        }
        lds_fence();
        bf16x8 a3h[2], a3l[2];
#pragma unroll
        for (int f2 = 0; f2 < 2; ++f2) {
            u32 hv[8];
#pragma unroll
            for (int j = 0; j < 8; ++j) hv[j] = hb[lc*33 + f2*16 + 8*g + j];
            FragU H, L;
#pragma unroll
            for (int w = 0; w < 4; ++w) {
                H.w[w] = (hv[2*w] & 0xffffu) | (hv[2*w+1] << 16);
                L.w[w] = (hv[2*w] >> 16)    | (hv[2*w+1] & 0xffff0000u);
            }
            a3h[f2] = H.v; a3l[f2] = L.v;
        }

        // ---- layer 3 (no relu) ----
        f32x16 acc3 = zero16();
#pragma unroll
        for (int f2 = 0; f2 < 2; ++f2) {
            FragU WH, WL;
            WH.u4 = sw4[(16 + 2*f2) * 64 + l];
            WL.u4 = sw4[(17 + 2*f2) * 64 + l];
            acc3 = mfma16(a3h[f2], WH.v, acc3);
            acc3 = mfma16(a3h[f2], WL.v, acc3);
            acc3 = mfma16(a3l[f2], WH.v, acc3);
        }
#pragma unroll
        for (int reg = 0; reg < 16; ++reg) {
            const int row = (reg & 3) + 8*(reg >> 2) + 4*g;
            hb[row * 33 + lc] = pack_split(acc3[reg] + bias3);
        }
        lds_fence();
        bf16x8 a4h[2], a4l[2];
#pragma unroll
        for (int f2 = 0; f2 < 2; ++f2) {
            u32 hv[8];
#pragma unroll
            for (int j = 0; j < 8; ++j) hv[j] = hb[lc*33 + f2*16 + 8*g + j];
            FragU H, L;
#pragma unroll
            for (int w = 0; w < 4; ++w) {
                H.w[w] = (hv[2*w] & 0xffffu) | (hv[2*w+1] << 16);
                L.w[w] = (hv[2*w] >> 16)    | (hv[2*w+1] & 0xffff0000u);
            }
            a4h[f2] = H.v; a4l[f2] = L.v;
        }

        // ---- heads: 4 N-tiles (2 heads each), select by t, fold into ys ----
        float ys[16];
#pragma unroll
        for (int reg = 0; reg < 16; ++reg) ys[reg] = 0.f;
#pragma unroll
        for (int n = 0; n < 4; ++n) {
            f32x16 hacc = zero16();
#pragma unroll
            for (int f2 = 0; f2 < 2; ++f2) {
                FragU WH, WL;
                WH.u4 = sw4[(20 + 2*n + f2) * 64 + l];           // HW1 hi (LDS)
                WL.u4 = wf4[(33 + 4*n + 2*f2) * 64 + l];         // HW1 lo (global)
                hacc = mfma16(a4h[f2], WH.v, hacc);
                hacc = mfma16(a4h[f2], WL.v, hacc);
                hacc = mfma16(a4l[f2], WH.v, hacc);
            }
            const int myhead = n*2 + hh_half;
#pragma unroll
            for (int reg = 0; reg < 16; ++reg) {
                const float hhv = fmaxf(hacc[reg] + hb1v[n], 0.f) * hw2v[n];
                ys[reg] += (t_r[reg] == myhead) ? hhv : 0.f;
            }
        }

        // ---- reduce over the 16 ph-lanes (DPP) + combine head-halves ----
#pragma unroll
        for (int reg = 0; reg < 16; ++reg) {
            float v = ys[reg];
            v = dpp_add<0xB1>(v);     // quad_perm [1,0,3,2]  (xor 1)
            v = dpp_add<0x4E>(v);     // quad_perm [2,3,0,1]  (xor 2)
            v = dpp_add<0x124>(v);    // row_ror:4
            v = dpp_add<0x128>(v);    // row_ror:8
            v += __shfl_xor(v, 16);   // combine the two head-halves
            ys[reg] = v;
        }

        if (lc == 0) {
#pragma unroll
            for (int qq = 0; qq < 4; ++qq) {
                f32x4 o;
#pragma unroll
                for (int m = 0; m < 4; ++m)
                    o[m] = ys[qq*4 + m] + Hb2[t_r[qq*4 + m]];
                *(f32x4*)(out + tb + 8*qq + 4*g) = o;
            }
        }
    }
}

} // namespace

extern "C" void kernel_launch(void* const* d_in, const int* in_sizes, int n_in,
                              void* d_out, int out_size, void* d_ws, size_t ws_size,
                              hipStream_t stream)
{
    const float* x_cont = (const float*)d_in[0];
    const int*   x_cate = (const int*)  d_in[1];
    const int*   t      = (const int*)  d_in[2];
    const float* emb    = (const float*)d_in[3];
    const float* W1     = (const float*)d_in[4];
    const float* b1     = (const float*)d_in[5];
    const float* W2     = (const float*)d_in[6];
    const float* b2     = (const float*)d_in[7];
    const float* W3     = (const float*)d_in[8];
    const float* b3     = (const float*)d_in[9];
    const float* HW1    = (const float*)d_in[10];
    const float* Hb1    = (const float*)d_in[11];
    const float* HW2    = (const float*)d_in[12];
    const float* Hb2    = (const float*)d_in[13];
    float* out = (float*)d_out;

    ushort* WF = (ushort*)d_ws;
    ushort* eh = (ushort*)((char*)d_ws + kOffEH);
    ushort* el = (ushort*)((char*)d_ws + kOffEL);

    hipLaunchKernelGGL(build_wfrags, dim3(12), dim3(256), 0, stream, W1, W2, W3, HW1, WF);
    hipLaunchKernelGGL(build_embsplit, dim3((kNCate*kVocab + 255)/256), dim3(256), 0, stream,
                       emb, eh, el);

    const int grid = kRows / 256;   // 2048 blocks, 256 rows each
    hipLaunchKernelGGL(fused_main, dim3(grid), dim3(256), 0, stream,
                       x_cont, x_cate, t, WF, eh, el,
                       b1, b2, b3, Hb1, HW2, Hb2, out);
}

// Round 9
// 95.028 us; speedup vs baseline: 2.9702x; 1.6501x over previous
//
#include <hip/hip_runtime.h>

namespace {

typedef float  f32x4  __attribute__((ext_vector_type(4)));
typedef float  f32x16 __attribute__((ext_vector_type(16)));
typedef short  bf16x8 __attribute__((ext_vector_type(8)));
typedef int    i32x4  __attribute__((ext_vector_type(4)));
typedef unsigned int u32;

constexpr int kRows  = 524288;
constexpr int kCont  = 64;
constexpr int kNCate = 16;
constexpr int kVocab = 1000;
constexpr int kEm    = 8;
constexpr int kRH    = 32;
constexpr int kPH    = 16;

constexpr int    kNFrag = 48;
constexpr size_t kOffEH = (size_t)kNFrag * 1024;    // 49152
constexpr size_t kOffEL = kOffEH + 256000;

__device__ inline u32 rne_hi(float x) {
    u32 u = __float_as_uint(x);
    return ((u + 0x7fffu + ((u >> 16) & 1u)) >> 16) & 0xffffu;
}
__device__ inline float hi_f32(u32 h) { return __uint_as_float(h << 16); }
// pack two floats as bf16 pair: a -> low16, b -> high16 (verified R6 math)
__device__ inline u32 pack2(float a, float b) {
    return rne_hi(a) | (rne_hi(b) << 16);
}

union FragU { u32 w[4]; bf16x8 v; uint4 u4; };

__device__ inline f32x16 mfma16(bf16x8 a, bf16x8 b, f32x16 c) {
    return __builtin_amdgcn_mfma_f32_32x32x16_bf16(a, b, c, 0, 0, 0);
}
__device__ inline f32x16 zero16() {
    f32x16 z;
#pragma unroll
    for (int i = 0; i < 16; ++i) z[i] = 0.f;
    return z;
}

// ---------------------------------------------------------------------------
// Pre-kernel 1 (UNCHANGED from R6; frag lane-mapping identical for A- and
// B-operand roles, so the same table serves the transposed computation).
// ---------------------------------------------------------------------------
__global__ __launch_bounds__(256) void build_wfrags(
    const float* __restrict__ W1, const float* __restrict__ W2,
    const float* __restrict__ W3, const float* __restrict__ HW1,
    ushort* __restrict__ WF)
{
    int gid = blockIdx.x * blockDim.x + threadIdx.x;
    if (gid >= kNFrag * 64) return;
    const int q = gid >> 6, l = gid & 63;
    const int lc = l & 31, g = l >> 5;

    const float* src; int k0, col, ldn, p;
    if (q < 12)      { src = W1; k0 = 16*q + 8*g;      col = lc; ldn = 32; p = 0; }
    else if (q < 24) { src = W1; k0 = 16*(q-12) + 8*g; col = lc; ldn = 32; p = 1; }
    else if (q < 28) { int u2 = q-24; src = W2; k0 = 16*(u2>>1) + 8*g; col = lc; ldn = 32; p = u2&1; }
    else if (q < 32) { int u2 = q-28; src = W3; k0 = 16*(u2>>1) + 8*g; col = lc; ldn = 32; p = u2&1; }
    else {
        int u2 = q-32; int n = u2>>2; int f = (u2>>1)&1; p = u2&1;
        int c128 = n*32 + lc; int head = c128 >> 4, ph = c128 & 15;
        src = HW1 + (size_t)head * kRH * kPH + ph;
        k0 = 16*f + 8*g; col = 0; ldn = kPH;
    }

    u32 hv[8];
#pragma unroll
    for (int j = 0; j < 8; ++j) {
        float w = src[(size_t)(k0 + j) * ldn + col];
        u32 h = rne_hi(w);
        hv[j] = (p == 0) ? h : rne_hi(w - hi_f32(h));
    }
    FragU fu;
#pragma unroll
    for (int w = 0; w < 4; ++w) fu.w[w] = hv[2*w] | (hv[2*w+1] << 16);
    ((uint4*)WF)[q * 64 + l] = fu.u4;
}

// ---------------------------------------------------------------------------
// Pre-kernel 2 (unchanged): emb -> bf16 hi/lo tables, 16B rows.
// ---------------------------------------------------------------------------
__global__ __launch_bounds__(256) void build_embsplit(
    const float* __restrict__ emb, ushort* __restrict__ eh, ushort* __restrict__ el)
{
    int r = blockIdx.x * blockDim.x + threadIdx.x;
    if (r >= kNCate * kVocab) return;
    const float* e = emb + (size_t)r * kEm;
    FragU H, L;
#pragma unroll
    for (int w = 0; w < 4; ++w) {
        float a = e[2*w], b = e[2*w+1];
        u32 ha = rne_hi(a), hb_ = rne_hi(b);
        u32 la = rne_hi(a - hi_f32(ha)), lb = rne_hi(b - hi_f32(hb_));
        H.w[w] = ha | (hb_ << 16);
        L.w[w] = la | (lb << 16);
    }
    ((uint4*)eh)[r] = H.u4;
    ((uint4*)el)[r] = L.u4;
}

// ---------------------------------------------------------------------------
// Transition: 16 per-lane activation values (lane=sample, regs=features via
// row(r,g)=(r&3)+8*(r>>2)+4g) -> two 16-k B-frags (hi+lo), fully in-register.
// Feature phi of sample lc lives in lane-group (phi>>2)&1, reg
// (phi&3)+4*(phi>>3). Lanes l and l^32 hold complementary quads.
// ---------------------------------------------------------------------------
__device__ inline void transition(const float* v, int g, FragU* H, FragU* L) {
    u32 hw[8], lw[8];
#pragma unroll
    for (int p = 0; p < 8; ++p) {
        float v0 = v[2*p], v1 = v[2*p+1];
        u32 h0 = rne_hi(v0), h1 = rne_hi(v1);
        hw[p] = h0 | (h1 << 16);
        lw[p] = pack2(v0 - hi_f32(h0), v1 - hi_f32(h1));
    }
#pragma unroll
    for (int f2 = 0; f2 < 2; ++f2) {
        u32 hp[4], lp[4];
#pragma unroll
        for (int p = 0; p < 4; ++p) {
            hp[p] = (u32)__shfl_xor((int)hw[4*f2 + p], 32);
            lp[p] = (u32)__shfl_xor((int)lw[4*f2 + p], 32);
        }
        // g=0 frag: [own0, own1, part0, part1]; g=1 frag: [part2, part3, own2, own3]
        H[f2].w[0] = g ? hp[2] : hw[4*f2+0];
        H[f2].w[1] = g ? hp[3] : hw[4*f2+1];
        H[f2].w[2] = g ? hw[4*f2+2] : hp[0];
        H[f2].w[3] = g ? hw[4*f2+3] : hp[1];
        L[f2].w[0] = g ? lp[2] : lw[4*f2+0];
        L[f2].w[1] = g ? lp[3] : lw[4*f2+1];
        L[f2].w[2] = g ? lw[4*f2+2] : lp[0];
        L[f2].w[3] = g ? lw[4*f2+3] : lp[1];
    }
}

// ---------------------------------------------------------------------------
// Main kernel, transposed: D = W^T @ X^T.  A = weight frags (row=lc=out-feat),
// B = activation frags (col=lc=sample).  C: col=lc=sample, row=feature via
// (reg&3)+8*(reg>>2)+4g.  No LDS transition buffers, no waitcnt fences.
// 4 waves/block, 1 M-tile (32 samples) per wave, grid 4096.
// ---------------------------------------------------------------------------
__global__ __launch_bounds__(256, 3) void fused_main(
    const float* __restrict__ xc, const int* __restrict__ xcate,
    const int* __restrict__ tptr,
    const ushort* __restrict__ WF,
    const ushort* __restrict__ embh, const ushort* __restrict__ embl,
    const float* __restrict__ b1, const float* __restrict__ b2,
    const float* __restrict__ b3, const float* __restrict__ Hb1,
    const float* __restrict__ HW2, const float* __restrict__ Hb2,
    float* __restrict__ out)
{
    __shared__ __align__(16) uint4 sW4[40 * 64];   // 40 KB: q0..31 + 8 HW1-hi
    __shared__ __align__(16) float sB[360];        // b1,b2,b3 | Hb1 | HW2 | Hb2

    const int tid = threadIdx.x;
    const uint4* wf4 = (const uint4*)WF;

#pragma unroll
    for (int it = 0; it < 10; ++it) {
        const int i = tid + 256 * it;
        const int s = i >> 6, l2 = i & 63;
        const int q = (s < 32) ? s : (2*s - 32);   // s>=32 -> HW1-hi q=32,34,..,46
        sW4[i] = wf4[q * 64 + l2];
    }
    // FIX vs R7/R8: blockDim is 256, sB has 360 entries -> strided loop.
    for (int i = tid; i < 360; i += 256) {
        float v;
        if      (i < 32)  v = b1[i];
        else if (i < 64)  v = b2[i - 32];
        else if (i < 96)  v = b3[i - 64];
        else if (i < 224) v = Hb1[i - 96];
        else if (i < 352) v = HW2[i - 224];
        else              v = Hb2[i - 352];
        sB[i] = v;
    }
    __syncthreads();

    const int wv = tid >> 6, l = tid & 63;
    const int lc = l & 31, g = l >> 5;
    const int tb = blockIdx.x * 128 + wv * 32;
    const int arow = tb + lc;                      // this lane's sample

    // ---- issue all global loads up front ----
    i32x4 cq[4];
    {
        const i32x4* cr4 = (const i32x4*)(xcate + (size_t)arow * kNCate);
#pragma unroll
        for (int q = 0; q < 4; ++q) cq[q] = cr4[q];
    }
    f32x4 xa[8];
    {
        const f32x4* xr4 = (const f32x4*)(xc + (size_t)arow * kCont);
#pragma unroll
        for (int f = 0; f < 4; ++f) { xa[2*f] = xr4[4*f + 2*g]; xa[2*f+1] = xr4[4*f + 2*g + 1]; }
    }
    uint4 ehv[8], elv[8];
#pragma unroll
    for (int i = 0; i < 8; ++i) {
        const int c   = 2*i + g;
        const int idx = cq[i >> 1][2*(i & 1) + g];
        const size_t ro = (size_t)(c * kVocab + idx);
        ehv[i] = ((const uint4*)embh)[ro];
        elv[i] = ((const uint4*)embl)[ro];
    }
    const int t_lane = tptr[arow];

    // ---- layer 1: acc = W1h@Xh + W1l@Xh + W1h@Xl over 12 k-frags ----
    f32x16 acca = zero16(), accb = zero16();
#pragma unroll
    for (int f = 0; f < 4; ++f) {                  // x_cont frags, runtime split
        FragU H, L;
#pragma unroll
        for (int w = 0; w < 4; ++w) {
            const f32x4& va = (w < 2) ? xa[2*f] : xa[2*f+1];
            const float v0 = va[2*(w & 1)], v1 = va[2*(w & 1) + 1];
            u32 h0 = rne_hi(v0), h1 = rne_hi(v1);
            H.w[w] = h0 | (h1 << 16);
            L.w[w] = pack2(v0 - hi_f32(h0), v1 - hi_f32(h1));
        }
        FragU WH, WL;
        WH.u4 = sW4[f * 64 + l];
        WL.u4 = sW4[(12 + f) * 64 + l];
        f32x16& acc = (f & 1) ? accb : acca;
        acc = mfma16(WH.v, H.v, acc);
        acc = mfma16(WL.v, H.v, acc);
        acc = mfma16(WH.v, L.v, acc);
    }
#pragma unroll
    for (int i = 0; i < 8; ++i) {                  // emb frags, pre-split
        const int f = 4 + i;
        FragU BH, BL, WH, WL;
        BH.u4 = ehv[i]; BL.u4 = elv[i];
        WH.u4 = sW4[f * 64 + l];
        WL.u4 = sW4[(12 + f) * 64 + l];
        f32x16& acc = (f & 1) ? accb : acca;
        acc = mfma16(WH.v, BH.v, acc);
        acc = mfma16(WL.v, BH.v, acc);
        acc = mfma16(WH.v, BL.v, acc);
    }

    // bias1 + relu  (bias varies across regs: b[row(r,g)] = quad at 8p+4g)
    float v1v[16];
    {
#pragma unroll
        for (int p = 0; p < 4; ++p) {
            f32x4 bq = *(const f32x4*)&sB[0 + 8*p + 4*g];
#pragma unroll
            for (int m = 0; m < 4; ++m)
                v1v[4*p + m] = fmaxf(acca[4*p + m] + accb[4*p + m] + bq[m], 0.f);
        }
    }
    FragU a2h[2], a2l[2];
    transition(v1v, g, a2h, a2l);

    // ---- layer 2 ----
    f32x16 acc2 = zero16();
#pragma unroll
    for (int f2 = 0; f2 < 2; ++f2) {
        FragU WH, WL;
        WH.u4 = sW4[(24 + 2*f2) * 64 + l];
        WL.u4 = sW4[(25 + 2*f2) * 64 + l];
        acc2 = mfma16(WH.v, a2h[f2].v, acc2);
        acc2 = mfma16(WL.v, a2h[f2].v, acc2);
        acc2 = mfma16(WH.v, a2l[f2].v, acc2);
    }
    float v2v[16];
    {
#pragma unroll
        for (int p = 0; p < 4; ++p) {
            f32x4 bq = *(const f32x4*)&sB[32 + 8*p + 4*g];
#pragma unroll
            for (int m = 0; m < 4; ++m)
                v2v[4*p + m] = fmaxf(acc2[4*p + m] + bq[m], 0.f);
        }
    }
    FragU a3h[2], a3l[2];
    transition(v2v, g, a3h, a3l);

    // ---- layer 3 (no relu) ----
    f32x16 acc3 = zero16();
#pragma unroll
    for (int f2 = 0; f2 < 2; ++f2) {
        FragU WH, WL;
        WH.u4 = sW4[(28 + 2*f2) * 64 + l];
        WL.u4 = sW4[(29 + 2*f2) * 64 + l];
        acc3 = mfma16(WH.v, a3h[f2].v, acc3);
        acc3 = mfma16(WL.v, a3h[f2].v, acc3);
        acc3 = mfma16(WH.v, a3l[f2].v, acc3);
    }
    float v3v[16];
    {
#pragma unroll
        for (int p = 0; p < 4; ++p) {
            f32x4 bq = *(const f32x4*)&sB[64 + 8*p + 4*g];
#pragma unroll
            for (int m = 0; m < 4; ++m)
                v3v[4*p + m] = acc3[4*p + m] + bq[m];
        }
    }
    FragU a4h[2], a4l[2];
    transition(v3v, g, a4h, a4l);

    // ---- heads: 4 A-tiles (2 heads each); lane epilogue selects its own t ----
    const f32x4 hb1q0 = *(const f32x4*)&sB[96  + t_lane*16 + 4*g];
    const f32x4 hb1q1 = *(const f32x4*)&sB[96  + t_lane*16 + 8 + 4*g];
    const f32x4 hw2q0 = *(const f32x4*)&sB[224 + t_lane*16 + 4*g];
    const f32x4 hw2q1 = *(const f32x4*)&sB[224 + t_lane*16 + 8 + 4*g];

    float ys = 0.f;
#pragma unroll
    for (int n = 0; n < 4; ++n) {
        f32x16 hacc = zero16();
#pragma unroll
        for (int f2 = 0; f2 < 2; ++f2) {
            FragU WH, WL;
            WH.u4 = sW4[(32 + 2*n + f2) * 64 + l];        // HW1-hi (LDS)
            WL.u4 = wf4[(33 + 4*n + 2*f2) * 64 + l];      // HW1-lo (global, L1)
            hacc = mfma16(WH.v, a4h[f2].v, hacc);
            hacc = mfma16(WL.v, a4h[f2].v, hacc);
            hacc = mfma16(WH.v, a4l[f2].v, hacc);
        }
        const bool sel = ((t_lane >> 1) == n);
        const bool half = (t_lane & 1);
#pragma unroll
        for (int j = 0; j < 8; ++j) {
            const float bb = (j < 4) ? hb1q0[j] : hb1q1[j - 4];
            const float ww = (j < 4) ? hw2q0[j] : hw2q1[j - 4];
            const float c0 = fmaxf(hacc[j]     + bb, 0.f) * ww;
            const float c1 = fmaxf(hacc[8 + j] + bb, 0.f) * ww;
            const float pick = half ? c1 : c0;
            ys += sel ? pick : 0.f;
        }
    }

    const float ytot = ys + __shfl_xor(ys, 32);
    if (g == 0)
        out[arow] = ytot + sB[352 + t_lane];
}

} // namespace

extern "C" void kernel_launch(void* const* d_in, const int* in_sizes, int n_in,
                              void* d_out, int out_size, void* d_ws, size_t ws_size,
                              hipStream_t stream)
{
    const float* x_cont = (const float*)d_in[0];
    const int*   x_cate = (const int*)  d_in[1];
    const int*   t      = (const int*)  d_in[2];
    const float* emb    = (const float*)d_in[3];
    const float* W1     = (const float*)d_in[4];
    const float* b1     = (const float*)d_in[5];
    const float* W2     = (const float*)d_in[6];
    const float* b2     = (const float*)d_in[7];
    const float* W3     = (const float*)d_in[8];
    const float* b3     = (const float*)d_in[9];
    const float* HW1    = (const float*)d_in[10];
    const float* Hb1    = (const float*)d_in[11];
    const float* HW2    = (const float*)d_in[12];
    const float* Hb2    = (const float*)d_in[13];
    float* out = (float*)d_out;

    ushort* WF = (ushort*)d_ws;
    ushort* eh = (ushort*)((char*)d_ws + kOffEH);
    ushort* el = (ushort*)((char*)d_ws + kOffEL);

    hipLaunchKernelGGL(build_wfrags, dim3(12), dim3(256), 0, stream, W1, W2, W3, HW1, WF);
    hipLaunchKernelGGL(build_embsplit, dim3((kNCate*kVocab + 255)/256), dim3(256), 0, stream,
                       emb, eh, el);

    const int grid = kRows / 128;   // 4096 blocks, 128 rows each (32/wave)
    hipLaunchKernelGGL(fused_main, dim3(grid), dim3(256), 0, stream,
                       x_cont, x_cate, t, WF, eh, el,
                       b1, b2, b3, Hb1, HW2, Hb2, out);
}